// Round 5
// baseline (114.970 us; speedup 1.0000x reference)
//
#include <hip/hip_runtime.h>
#include <cstddef>

typedef float floatx4 __attribute__((ext_vector_type(4)));

// ---- real-basis CG constants ----
#define K_A 0.2390457218668787f    // 2/sqrt(70)
#define K_B 0.11952286093343936f   // 1/sqrt(70)
#define K_G 0.20701966780270626f   // 3/sqrt(210)

struct C2T {
    float v[5][5][5];
    constexpr C2T() : v{} {
        v[2][2][2] = -K_A;
        v[2][1][1] = -K_B; v[2][3][3] = -K_B; v[1][2][1] = -K_B;
        v[3][2][3] = -K_B; v[1][1][2] = -K_B; v[3][3][2] = -K_B;
        v[2][0][0] =  K_A; v[2][4][4] =  K_A; v[0][2][0] =  K_A;
        v[4][2][4] =  K_A; v[0][0][2] =  K_A; v[4][4][2] =  K_A;
        v[1][1][4] =  K_G; v[4][1][1] =  K_G; v[1][4][1] =  K_G;
        v[3][3][4] = -K_G; v[4][3][3] = -K_G; v[3][4][3] = -K_G;
        v[1][3][0] = -K_G; v[3][1][0] = -K_G; v[0][1][3] = -K_G;
        v[0][3][1] = -K_G; v[1][0][3] = -K_G; v[3][0][1] = -K_G;
    }
};
constexpr C2T C2c{};

// ---- fused: zero graph bins + build padded pos4 stash (in d_out tail) ----
__global__ __launch_bounds__(256) void pos4zero_kernel(
    const float* __restrict__ pos, float* __restrict__ stash,
    float* __restrict__ out, int N, int G)
{
    int i = blockIdx.x * blockDim.x + threadIdx.x;
    if (i < G) out[i] = 0.0f;
    if (i < N) {
        floatx4 v;
        v.x = pos[3*i]; v.y = pos[3*i+1]; v.z = pos[3*i+2]; v.w = 0.0f;
        *((floatx4*)stash + i) = v;
    }
}

// ---- atom kernel: direct AoS reads ----
__global__ __launch_bounds__(256) void atom_kernel(
    const float* __restrict__ Hs, const float* __restrict__ Hp,
    const float* __restrict__ Hd, const int* __restrict__ gid,
    const float* __restrict__ wsp, const float* __restrict__ wpp,
    const float* __restrict__ wdp, float* __restrict__ out, int N)
{
    int n = blockIdx.x * blockDim.x + threadIdx.x;
    if (n >= N) return;
    const float ws = wsp[0], wp = wpp[0], wd = wdp[0];

    const float4 hs = *(const float4*)(Hs + (size_t)n * 4);
    const float ws2 = ws * ws;
    const float ts = (ws2 * ws2) * hs.x * hs.y * hs.z * hs.w;
    float total = ts * ts * (1.0f / 16.0f);

    {
        const float* hp = Hp + (size_t)n * 27;
        const float cp = -wp * 0.70710678118654752f;  // -wp*sqrt(3)/sqrt(6)
        float t[3][3] = {{1,0,0},{0,1,0},{0,0,1}};
        #pragma unroll
        for (int s = 0; s < 3; s++) {
            #pragma unroll
            for (int b = 0; b < 3; b++) {
                const float h0 = hp[s*9 + b*3 + 0];
                const float h1 = hp[s*9 + b*3 + 1];
                const float h2 = hp[s*9 + b*3 + 2];
                const float c0 = t[b][1]*h2 - t[b][2]*h1;
                const float c1 = t[b][2]*h0 - t[b][0]*h2;
                const float c2 = t[b][0]*h1 - t[b][1]*h0;
                t[b][0] = cp * c0; t[b][1] = cp * c1; t[b][2] = cp * c2;
            }
        }
        const float u0 = t[0][0] + t[1][0] + t[2][0];
        const float u1 = t[0][1] + t[1][1] + t[2][1];
        const float u2 = t[0][2] + t[1][2] + t[2][2];
        total += (u0*u0 + u1*u1 + u2*u2) * (1.0f / 9.0f);
    }

    {
        const float* hd = Hd + (size_t)n * 50;
        const float sd = wd * 2.23606797749978969f;   // wd*sqrt(5)
        float u[5] = {0, 0, 0, 0, 0};
        #pragma unroll
        for (int b = 0; b < 5; b++) {
            float h0r[5], h1r[5], t1r[5];
            #pragma unroll
            for (int j = 0; j < 5; j++) h0r[j] = hd[b*5 + j];
            #pragma unroll
            for (int k = 0; k < 5; k++) {
                float acc = 0.0f;
                #pragma unroll
                for (int j = 0; j < 5; j++) acc += C2c.v[b][j][k] * h0r[j];
                t1r[k] = sd * acc;
            }
            #pragma unroll
            for (int j = 0; j < 5; j++) h1r[j] = hd[25 + b*5 + j];
            #pragma unroll
            for (int k = 0; k < 5; k++) {
                float acc = 0.0f;
                #pragma unroll
                for (int i = 0; i < 5; i++)
                    #pragma unroll
                    for (int j = 0; j < 5; j++)
                        acc += C2c.v[i][j][k] * (t1r[i] * h1r[j]);
                u[k] += sd * acc;
            }
        }
        total += (u[0]*u[0] + u[1]*u[1] + u[2]*u[2] + u[3]*u[3] + u[4]*u[4]) * 0.25f;
    }

    unsafeAtomicAdd(out + gid[n], total);
}

__device__ __forceinline__ float bumpf(float d) {
    // 1.14136 * sqrt(10) * exp(2 - 2/(1-d^2)); caller guarantees d^2 <= 1
    const float SC = 1.14136f * 3.16227766016838f;
    const float denom = 1.0f - d * d;                 // in [0,1]
    const float inv = __builtin_amdgcn_rcpf(denom);   // denom=0 -> inf -> exp(-inf)=0
    return SC * __expf(2.0f - 2.0f * inv);
}

// ---- edge kernel over range [e_begin, e_end): float4-stash or raw-float3 ----
template <int USE4>
__global__ __launch_bounds__(256) void edge_kernel(
    const void* __restrict__ posv, const int* __restrict__ src,
    const int* __restrict__ dst, float* __restrict__ emb,
    int e_begin, int e_end)
{
    __shared__ float lds[256 * 11];   // stride 11: conflict-free scatter
    const int tid  = threadIdx.x;
    const int base = e_begin + blockIdx.x * 256;
    const int nb   = min(256, e_end - base);
    const int e    = base + tid;

    if (tid < nb) {
        const int s = __builtin_nontemporal_load(src + e);
        const int d = __builtin_nontemporal_load(dst + e);
        float dx, dy, dz;
        if (USE4) {
            const floatx4* p4 = (const floatx4*)posv;
            const floatx4 a = p4[s];
            const floatx4 b = p4[d];
            dx = b.x - a.x; dy = b.y - a.y; dz = b.z - a.z;
        } else {
            const float* p = (const float*)posv;
            dx = p[d*3+0] - p[s*3+0];
            dy = p[d*3+1] - p[s*3+1];
            dz = p[d*3+2] - p[s*3+2];
        }
        const float r  = sqrtf(dx*dx + dy*dy + dz*dz + 1e-12f);
        const float rs = r * 2.2f;                 // r / (5/11)
        const float fq = floorf(rs);
        const int   qa = (int)fq;
        const float va = bumpf(rs - fq);           // slot qa   (1-based)
        const float vb = bumpf(rs - fq - 1.0f);    // slot qa+1
        #pragma unroll
        for (int q = 0; q < 10; q++) {
            float v = 0.0f;
            v = (qa == q + 1) ? va : v;
            v = (qa == q)     ? vb : v;
            lds[tid * 11 + q] = v;
        }
    }
    __syncthreads();

    float* outp = emb + (size_t)base * 10;
    if (nb == 256) {
        #pragma unroll
        for (int it = 0; it < 3; it++) {
            const int t4 = tid + it * 256;        // float4 index in [0,640)
            if (t4 < 640) {
                const int j = t4 * 4;
                floatx4 v;
                v.x = lds[((j+0)/10)*11 + (j+0)%10];
                v.y = lds[((j+1)/10)*11 + (j+1)%10];
                v.z = lds[((j+2)/10)*11 + (j+2)%10];
                v.w = lds[((j+3)/10)*11 + (j+3)%10];
                __builtin_nontemporal_store(v, (floatx4*)outp + t4);
            }
        }
    } else {
        const int tot = nb * 10;
        for (int k = tid; k < tot; k += 256)
            outp[k] = lds[(k/10)*11 + k%10];
    }
}

extern "C" void kernel_launch(void* const* d_in, const int* in_sizes, int n_in,
                              void* d_out, int out_size, void* d_ws, size_t ws_size,
                              hipStream_t stream) {
    const float* Hs  = (const float*)d_in[0];
    const float* Hp  = (const float*)d_in[1];
    const float* Hd  = (const float*)d_in[2];
    const float* pos = (const float*)d_in[3];
    const float* wsp = (const float*)d_in[4];
    const float* wpp = (const float*)d_in[5];
    const float* wdp = (const float*)d_in[6];
    const int* esrc  = (const int*)d_in[7];
    const int* edst  = (const int*)d_in[8];
    const int* gid   = (const int*)d_in[9];

    const int N = in_sizes[0] / 4;
    const int E = in_sizes[7];
    const int G = out_size - 10 * E;   // 2000

    float* out = (float*)d_out;
    float* emb = out + G;

    // pos4 stash lives in the TAIL of d_out (emb slots of the last edges),
    // which edgeA never touches and edgeB overwrites afterwards.
    int stash_abs = (out_size - 4 * N) & ~3;            // 16B-aligned float idx
    int Esplit = (stash_abs - G) / 10;                  // edges safe below stash
    if (Esplit > E) Esplit = E;

    if (Esplit > 0 && stash_abs > G) {
        float* stash = out + stash_abs;
        const int T0 = (N > G ? N : G);
        pos4zero_kernel<<<(T0 + 255) / 256, 256, 0, stream>>>(pos, stash, out, N, G);
        atom_kernel<<<(N + 255) / 256, 256, 0, stream>>>(Hs, Hp, Hd, gid, wsp, wpp, wdp, out, N);
        edge_kernel<1><<<(Esplit + 255) / 256, 256, 0, stream>>>(stash, esrc, edst, emb, 0, Esplit);
        if (E > Esplit) {
            const int nB = E - Esplit;
            edge_kernel<0><<<(nB + 255) / 256, 256, 0, stream>>>(pos, esrc, edst, emb, Esplit, E);
        }
    } else {
        // fallback: no room for stash — raw float3 path for everything
        pos4zero_kernel<<<(G + 255) / 256, 256, 0, stream>>>(pos, out, out, 0, G);
        atom_kernel<<<(N + 255) / 256, 256, 0, stream>>>(Hs, Hp, Hd, gid, wsp, wpp, wdp, out, N);
        edge_kernel<0><<<(E + 255) / 256, 256, 0, stream>>>(pos, esrc, edst, emb, 0, E);
    }
}

// Round 6
// 105.830 us; speedup vs baseline: 1.0864x; 1.0864x over previous
//
#include <hip/hip_runtime.h>
#include <cstddef>

typedef float floatx4 __attribute__((ext_vector_type(4)));

// ---- real-basis CG constants ----
#define K_A 0.2390457218668787f    // 2/sqrt(70)
#define K_B 0.11952286093343936f   // 1/sqrt(70)
#define K_G 0.20701966780270626f   // 3/sqrt(210)

struct C2T {
    float v[5][5][5];
    constexpr C2T() : v{} {
        v[2][2][2] = -K_A;
        v[2][1][1] = -K_B; v[2][3][3] = -K_B; v[1][2][1] = -K_B;
        v[3][2][3] = -K_B; v[1][1][2] = -K_B; v[3][3][2] = -K_B;
        v[2][0][0] =  K_A; v[2][4][4] =  K_A; v[0][2][0] =  K_A;
        v[4][2][4] =  K_A; v[0][0][2] =  K_A; v[4][4][2] =  K_A;
        v[1][1][4] =  K_G; v[4][1][1] =  K_G; v[1][4][1] =  K_G;
        v[3][3][4] = -K_G; v[4][3][3] = -K_G; v[3][4][3] = -K_G;
        v[1][3][0] = -K_G; v[3][1][0] = -K_G; v[0][1][3] = -K_G;
        v[0][3][1] = -K_G; v[1][0][3] = -K_G; v[3][0][1] = -K_G;
    }
};
constexpr C2T C2c{};

// ---- fused: zero graph bins + build padded pos4 stash (in d_out tail) ----
__global__ __launch_bounds__(256) void pos4zero_kernel(
    const float* __restrict__ pos, float* __restrict__ stash,
    float* __restrict__ out, int N, int G)
{
    int i = blockIdx.x * blockDim.x + threadIdx.x;
    if (i < G) out[i] = 0.0f;
    if (i < N) {
        floatx4 v;
        v.x = pos[3*i]; v.y = pos[3*i+1]; v.z = pos[3*i+2]; v.w = 0.0f;
        *((floatx4*)stash + i) = v;
    }
}

// ---- atom kernel: direct AoS reads ----
__global__ __launch_bounds__(256) void atom_kernel(
    const float* __restrict__ Hs, const float* __restrict__ Hp,
    const float* __restrict__ Hd, const int* __restrict__ gid,
    const float* __restrict__ wsp, const float* __restrict__ wpp,
    const float* __restrict__ wdp, float* __restrict__ out, int N)
{
    int n = blockIdx.x * blockDim.x + threadIdx.x;
    if (n >= N) return;
    const float ws = wsp[0], wp = wpp[0], wd = wdp[0];

    const float4 hs = *(const float4*)(Hs + (size_t)n * 4);
    const float ws2 = ws * ws;
    const float ts = (ws2 * ws2) * hs.x * hs.y * hs.z * hs.w;
    float total = ts * ts * (1.0f / 16.0f);

    {
        const float* hp = Hp + (size_t)n * 27;
        const float cp = -wp * 0.70710678118654752f;  // -wp*sqrt(3)/sqrt(6)
        float t[3][3] = {{1,0,0},{0,1,0},{0,0,1}};
        #pragma unroll
        for (int s = 0; s < 3; s++) {
            #pragma unroll
            for (int b = 0; b < 3; b++) {
                const float h0 = hp[s*9 + b*3 + 0];
                const float h1 = hp[s*9 + b*3 + 1];
                const float h2 = hp[s*9 + b*3 + 2];
                const float c0 = t[b][1]*h2 - t[b][2]*h1;
                const float c1 = t[b][2]*h0 - t[b][0]*h2;
                const float c2 = t[b][0]*h1 - t[b][1]*h0;
                t[b][0] = cp * c0; t[b][1] = cp * c1; t[b][2] = cp * c2;
            }
        }
        const float u0 = t[0][0] + t[1][0] + t[2][0];
        const float u1 = t[0][1] + t[1][1] + t[2][1];
        const float u2 = t[0][2] + t[1][2] + t[2][2];
        total += (u0*u0 + u1*u1 + u2*u2) * (1.0f / 9.0f);
    }

    {
        const float* hd = Hd + (size_t)n * 50;
        const float sd = wd * 2.23606797749978969f;   // wd*sqrt(5)
        float u[5] = {0, 0, 0, 0, 0};
        #pragma unroll
        for (int b = 0; b < 5; b++) {
            float h0r[5], h1r[5], t1r[5];
            #pragma unroll
            for (int j = 0; j < 5; j++) h0r[j] = hd[b*5 + j];
            #pragma unroll
            for (int k = 0; k < 5; k++) {
                float acc = 0.0f;
                #pragma unroll
                for (int j = 0; j < 5; j++) acc += C2c.v[b][j][k] * h0r[j];
                t1r[k] = sd * acc;
            }
            #pragma unroll
            for (int j = 0; j < 5; j++) h1r[j] = hd[25 + b*5 + j];
            #pragma unroll
            for (int k = 0; k < 5; k++) {
                float acc = 0.0f;
                #pragma unroll
                for (int i = 0; i < 5; i++)
                    #pragma unroll
                    for (int j = 0; j < 5; j++)
                        acc += C2c.v[i][j][k] * (t1r[i] * h1r[j]);
                u[k] += sd * acc;
            }
        }
        total += (u[0]*u[0] + u[1]*u[1] + u[2]*u[2] + u[3]*u[3] + u[4]*u[4]) * 0.25f;
    }

    unsafeAtomicAdd(out + gid[n], total);
}

__device__ __forceinline__ float bumpf(float d) {
    // 1.14136 * sqrt(10) * exp(2 - 2/(1-d^2)); caller guarantees d^2 <= 1
    const float SC = 1.14136f * 3.16227766016838f;
    const float denom = 1.0f - d * d;                 // in [0,1]
    const float inv = __builtin_amdgcn_rcpf(denom);   // denom=0 -> inf -> exp(-inf)=0
    return SC * __expf(2.0f - 2.0f * inv);
}

// ---- edge kernel over range [e_begin, e_end): float4-stash or raw-float3 ----
// Plain (cached) loads and stores throughout — NT hints removed (R5 postmortem).
template <int USE4>
__global__ __launch_bounds__(256) void edge_kernel(
    const void* __restrict__ posv, const int* __restrict__ src,
    const int* __restrict__ dst, float* __restrict__ emb,
    int e_begin, int e_end)
{
    __shared__ float lds[256 * 11];   // stride 11: conflict-free scatter
    const int tid  = threadIdx.x;
    const int base = e_begin + blockIdx.x * 256;
    const int nb   = min(256, e_end - base);
    const int e    = base + tid;

    if (tid < nb) {
        const int s = src[e];
        const int d = dst[e];
        float dx, dy, dz;
        if (USE4) {
            const floatx4* p4 = (const floatx4*)posv;
            const floatx4 a = p4[s];
            const floatx4 b = p4[d];
            dx = b.x - a.x; dy = b.y - a.y; dz = b.z - a.z;
        } else {
            const float* p = (const float*)posv;
            dx = p[d*3+0] - p[s*3+0];
            dy = p[d*3+1] - p[s*3+1];
            dz = p[d*3+2] - p[s*3+2];
        }
        const float r  = sqrtf(dx*dx + dy*dy + dz*dz + 1e-12f);
        const float rs = r * 2.2f;                 // r / (5/11)
        const float fq = floorf(rs);
        const int   qa = (int)fq;
        const float va = bumpf(rs - fq);           // slot qa   (1-based)
        const float vb = bumpf(rs - fq - 1.0f);    // slot qa+1
        #pragma unroll
        for (int q = 0; q < 10; q++) {
            float v = 0.0f;
            v = (qa == q + 1) ? va : v;
            v = (qa == q)     ? vb : v;
            lds[tid * 11 + q] = v;
        }
    }
    __syncthreads();

    float* outp = emb + (size_t)base * 10;
    if (nb == 256) {
        #pragma unroll
        for (int it = 0; it < 3; it++) {
            const int t4 = tid + it * 256;        // float4 index in [0,640)
            if (t4 < 640) {
                const int j = t4 * 4;
                floatx4 v;
                v.x = lds[((j+0)/10)*11 + (j+0)%10];
                v.y = lds[((j+1)/10)*11 + (j+1)%10];
                v.z = lds[((j+2)/10)*11 + (j+2)%10];
                v.w = lds[((j+3)/10)*11 + (j+3)%10];
                *((floatx4*)outp + t4) = v;
            }
        }
    } else {
        const int tot = nb * 10;
        for (int k = tid; k < tot; k += 256)
            outp[k] = lds[(k/10)*11 + k%10];
    }
}

extern "C" void kernel_launch(void* const* d_in, const int* in_sizes, int n_in,
                              void* d_out, int out_size, void* d_ws, size_t ws_size,
                              hipStream_t stream) {
    const float* Hs  = (const float*)d_in[0];
    const float* Hp  = (const float*)d_in[1];
    const float* Hd  = (const float*)d_in[2];
    const float* pos = (const float*)d_in[3];
    const float* wsp = (const float*)d_in[4];
    const float* wpp = (const float*)d_in[5];
    const float* wdp = (const float*)d_in[6];
    const int* esrc  = (const int*)d_in[7];
    const int* edst  = (const int*)d_in[8];
    const int* gid   = (const int*)d_in[9];

    const int N = in_sizes[0] / 4;
    const int E = in_sizes[7];
    const int G = out_size - 10 * E;   // 2000

    float* out = (float*)d_out;
    float* emb = out + G;

    // pos4 stash lives in the TAIL of d_out (emb slots of the last edges),
    // which edgeA never touches and edgeB overwrites afterwards.
    int stash_abs = (out_size - 4 * N) & ~3;            // 16B-aligned float idx
    int Esplit = (stash_abs - G) / 10;                  // edges safe below stash
    if (Esplit > E) Esplit = E;

    if (Esplit > 0 && stash_abs > G) {
        float* stash = out + stash_abs;
        const int T0 = (N > G ? N : G);
        pos4zero_kernel<<<(T0 + 255) / 256, 256, 0, stream>>>(pos, stash, out, N, G);
        atom_kernel<<<(N + 255) / 256, 256, 0, stream>>>(Hs, Hp, Hd, gid, wsp, wpp, wdp, out, N);
        edge_kernel<1><<<(Esplit + 255) / 256, 256, 0, stream>>>(stash, esrc, edst, emb, 0, Esplit);
        if (E > Esplit) {
            const int nB = E - Esplit;
            edge_kernel<0><<<(nB + 255) / 256, 256, 0, stream>>>(pos, esrc, edst, emb, Esplit, E);
        }
    } else {
        // fallback: no room for stash — raw float3 path for everything
        pos4zero_kernel<<<(G + 255) / 256, 256, 0, stream>>>(pos, out, out, 0, G);
        atom_kernel<<<(N + 255) / 256, 256, 0, stream>>>(Hs, Hp, Hd, gid, wsp, wpp, wdp, out, N);
        edge_kernel<0><<<(E + 255) / 256, 256, 0, stream>>>(pos, esrc, edst, emb, 0, E);
    }
}